// Round 8
// baseline (7303.721 us; speedup 1.0000x reference)
//
#include <hip/hip_runtime.h>
#include <hip/hip_bf16.h>

// MDGCRN hybrid: fp32 encoder (argmax-exact path) + bf16-MFMA decoder.
// R8: k_mm2F retiled 128->64 rows/block, grid (8,1,64)=512 blocks (2 blocks/CU,
//     8 waves/CU) to fix R7's 1-block/CU occupancy ceiling. Pairing kept.
//     Bit-exact vs R7. Decoder = R3.

typedef __attribute__((ext_vector_type(8))) short s8v;
typedef __attribute__((ext_vector_type(4))) float f4v;
typedef __attribute__((ext_vector_type(4))) unsigned short u4v;

__device__ __forceinline__ float b2f(unsigned short u){
  union{unsigned int i; float f;} v; v.i = ((unsigned int)u)<<16; return v.f;
}
__device__ __forceinline__ unsigned short f2b(float f){
  union{float f; unsigned int i;} v; v.f = f;
  unsigned int r = v.i + 0x7fff + ((v.i >> 16) & 1);   // RNE (finite inputs only)
  return (unsigned short)(r >> 16);
}

__global__ void k_zero16(uint4* p, int n){
  int i = blockIdx.x*256 + threadIdx.x;
  if (i < n) p[i] = make_uint4(0,0,0,0);
}

// ======================= fp32 ENCODER =======================

__global__ void k_reorderF(const float* __restrict__ W, float* __restrict__ Wr,
                           int HC, int NEX, int SEGW, int J){
  int idx = blockIdx.x*256 + threadIdx.x;
  int K = 3*SEGW;
  if (idx >= K*J) return;
  int k = idx / J, j = idx - k*J;
  int seg = k / SEGW, c = k - seg*SEGW;
  int CIN = HC + NEX;
  float v = 0.f;
  if (c < HC)       v = W[(size_t)(seg*CIN + NEX + c)*J + j];
  else if (c < CIN) v = W[(size_t)(seg*CIN + (c-HC))*J + j];
  Wr[(size_t)k*J + j] = v;
}

// A2e = 2*A@A - I   (512x512)
__global__ __launch_bounds__(256) void k_a2e(const float* __restrict__ A,
                                             float* __restrict__ A2e){
  __shared__ __align__(16) float As[32][132];
  __shared__ __align__(16) float Bs[32][132];
  int t = threadIdx.x;
  int r0 = (blockIdx.x & 3) * 128;
  int c0 = (blockIdx.x >> 2) * 128;
  int tr = t & 15, tc = t >> 4;
  float acc[8][8];
  #pragma unroll
  for (int i=0;i<8;i++)
    #pragma unroll
    for (int j=0;j<8;j++) acc[i][j]=0.f;
  for (int k0=0;k0<512;k0+=32){
    #pragma unroll
    for (int i=0;i<4;i++){
      int s = t + i*256;
      int k = s & 31, rq = s >> 5;
      const float* ap = A + (size_t)(r0 + rq*4)*512 + k0 + k;
      float4 v;
      v.x = ap[0]; v.y = ap[512]; v.z = ap[1024]; v.w = ap[1536];
      *(float4*)&As[k][rq*4] = v;
    }
    #pragma unroll
    for (int i=0;i<4;i++){
      int s = t + i*256;
      int k = s >> 5, cq = s & 31;
      float4 v = *(const float4*)(A + (size_t)(k0+k)*512 + c0 + cq*4);
      *(float4*)&Bs[k][cq*4] = v;
    }
    __syncthreads();
    #pragma unroll 8
    for (int k=0;k<32;k++){
      float a[8], b[8];
      *(float4*)&a[0] = *(const float4*)&As[k][tr*4];
      *(float4*)&a[4] = *(const float4*)&As[k][64+tr*4];
      *(float4*)&b[0] = *(const float4*)&Bs[k][tc*4];
      *(float4*)&b[4] = *(const float4*)&Bs[k][64+tc*4];
      #pragma unroll
      for (int i=0;i<8;i++)
        #pragma unroll
        for (int j=0;j<8;j++) acc[i][j] += a[i]*b[j];
    }
    __syncthreads();
  }
  #pragma unroll
  for (int i=0;i<8;i++){
    int r = r0 + (i<4 ? tr*4+i : 64+tr*4+i-4);
    #pragma unroll
    for (int j=0;j<8;j++){
      int c = c0 + (j<4 ? tc*4+j : 64+tc*4+j-4);
      A2e[(size_t)r*512 + c] = 2.f*acc[i][j] - (r==c ? 1.f : 0.f);
    }
  }
}

// Fused dual conv x dual batch: G1=A@G0, G2=A2e@G0 for bb=z AND bb=z+64,
// sharing staged A/A2e. seg0=[h|x] written as side effect.
// feats row layout (204): [h 0..63 | x 64 | pad | G1 68..131 | pad | G2 136..199 | pad]
// Block 64 rows x 64 cols, 256 thr; TM4 x TN4 x 2mat x 2bb. Grid (8,1,64).
__global__ __launch_bounds__(256) void k_mm2F(
    const float* __restrict__ A, const float* __restrict__ A2e,
    const float* __restrict__ hsrc,             // [row][64] row-major (128*512 rows)
    const float* __restrict__ xa, const float* __restrict__ xb,  // (64,12,512)
    int tstep, float* __restrict__ feats)
{
  __shared__ __align__(16) float As[32][68];
  __shared__ __align__(16) float A2s[32][68];
  __shared__ __align__(16) float Bs0[32][68];
  __shared__ __align__(16) float Bs1[32][68];
  const int t = threadIdx.x;
  const int z = blockIdx.z;                    // bb0=z (x), bb1=z+64 (x_his)
  const int n0 = blockIdx.x * 64;
  const int tr = t & 15, tc = t >> 4;
  const int xrow = t & 63, xmat = (t >> 6) & 1, xbb = t >> 7;
  const float* xp0 = xa + ((size_t)z*12 + tstep)*512;
  const float* xp1 = xb + ((size_t)z*12 + tstep)*512;
  float acc[2][2][4][4];                       // [mat][bb][i][j]
  #pragma unroll
  for (int m=0;m<2;m++)
    #pragma unroll
    for (int b=0;b<2;b++)
      #pragma unroll
      for (int i=0;i<4;i++)
        #pragma unroll
        for (int j=0;j<4;j++) acc[m][b][i][j]=0.f;
  float xacc = 0.f;

  for (int k0=0;k0<512;k0+=32){
    // A/A2e stage: column loads -> b128 transpose writes (64 rows x 32 k)
    #pragma unroll
    for (int i=0;i<2;i++){
      int s = t + i*256;
      int k = s & 31, rq = s >> 5;             // rq 0..15 -> rows rq*4..rq*4+3
      const float* ap  = A   + (size_t)(n0 + rq*4)*512 + k0 + k;
      const float* a2p = A2e + (size_t)(n0 + rq*4)*512 + k0 + k;
      float4 v, w;
      v.x = ap[0];  v.y = ap[512];  v.z = ap[1024];  v.w = ap[1536];
      w.x = a2p[0]; w.y = a2p[512]; w.z = a2p[1024]; w.w = a2p[1536];
      *(float4*)&As[k][rq*4]  = v;
      *(float4*)&A2s[k][rq*4] = w;
    }
    // B stage for both batches
    #pragma unroll
    for (int i=0;i<2;i++){
      int s = t + i*256;
      int k = s >> 4, cq = s & 15;
      *(float4*)&Bs0[k][cq*4] = *(const float4*)(hsrc + (size_t)(z*512 + k0 + k)*64 + cq*4);
      *(float4*)&Bs1[k][cq*4] = *(const float4*)(hsrc + (size_t)((z+64)*512 + k0 + k)*64 + cq*4);
    }
    if (t < 32)      Bs0[t][64]    = xp0[k0 + t];
    else if (t < 64) Bs1[t-32][64] = xp1[k0 + t - 32];
    __syncthreads();
    #pragma unroll 4
    for (int k=0;k<32;k++){
      float a1[4], a2[4], b0[4], b1[4];
      *(float4*)&a1[0] = *(const float4*)&As[k][tr*4];
      *(float4*)&a2[0] = *(const float4*)&A2s[k][tr*4];
      *(float4*)&b0[0] = *(const float4*)&Bs0[k][tc*4];
      *(float4*)&b1[0] = *(const float4*)&Bs1[k][tc*4];
      #pragma unroll
      for (int i=0;i<4;i++)
        #pragma unroll
        for (int j=0;j<4;j++){
          acc[0][0][i][j] += a1[i]*b0[j];
          acc[0][1][i][j] += a1[i]*b1[j];
          acc[1][0][i][j] += a2[i]*b0[j];
          acc[1][1][i][j] += a2[i]*b1[j];
        }
      float am = xmat ? A2s[k][xrow] : As[k][xrow];
      xacc += am * (xbb ? Bs1[k][64] : Bs0[k][64]);
    }
    // seg0 writeback for this block's own rows (Bs holds G0 rows k0..k0+31)
    if ((k0 >> 6) == (int)blockIdx.x){
      for (int s=t; s<1088; s+=256){          // 2 bb x 32 rows x 17 float4
        int sb = (s >= 544) ? 1 : 0;
        int ss = s - sb*544;
        int kk = ss/17, q = ss - kk*17;
        int bb = z + sb*64;
        float4 v;
        if (q < 16) v = sb ? *(const float4*)&Bs1[kk][q*4] : *(const float4*)&Bs0[kk][q*4];
        else        v = make_float4(sb ? Bs1[kk][64] : Bs0[kk][64], 0.f, 0.f, 0.f);
        *(float4*)(feats + (size_t)(bb*512 + k0 + kk)*204 + q*4) = v;
      }
    }
    __syncthreads();
  }
  #pragma unroll
  for (int bbi=0;bbi<2;bbi++){
    const int bb = z + bbi*64;
    #pragma unroll
    for (int i=0;i<4;i++){
      int row = n0 + tr*4 + i;
      float* fr = feats + (size_t)(bb*512 + row)*204;
      float4 v;
      v.x=acc[0][bbi][i][0]; v.y=acc[0][bbi][i][1];
      v.z=acc[0][bbi][i][2]; v.w=acc[0][bbi][i][3];
      *(float4*)(fr + 68 + tc*4) = v;
      v.x=acc[1][bbi][i][0]; v.y=acc[1][bbi][i][1];
      v.z=acc[1][bbi][i][2]; v.w=acc[1][bbi][i][3];
      *(float4*)(fr + 136 + tc*4) = v;
    }
  }
  feats[(size_t)((z + xbb*64)*512 + n0 + xrow)*204 + (xmat ? 136 : 68) + 64] = xacc;
}

// Gate: feats(204) @ Wr(204x128) -> sigmoid; cols<64: zh=s*h, cols>=64: rbuf=s
// Block 128 rows x 128 cols, TM8(4+4) x TN8(4+4).
__global__ __launch_bounds__(256) void k_gwG(
    const float* __restrict__ feats, const float* __restrict__ Wr,
    const float* __restrict__ bias,
    const float* __restrict__ hbuf, float* __restrict__ zh, float* __restrict__ rbuf)
{
  __shared__ __align__(16) float As[17][132];
  __shared__ __align__(16) float Ws[17][132];
  const int t = threadIdx.x;
  const int row0 = blockIdx.x * 128;
  const int tr = t & 15, tc = t >> 4;
  float acc[2][2][4][4];                       // [rg][cg][i][j]
  #pragma unroll
  for (int rg=0;rg<2;rg++)
    #pragma unroll
    for (int cg=0;cg<2;cg++)
      #pragma unroll
      for (int i=0;i<4;i++)
        #pragma unroll
        for (int j=0;j<4;j++) acc[rg][cg][i][j]=0.f;
  for (int kc=0; kc<204; kc+=17){
    for (int s=t; s<2176; s+=256){         // As: 128 rows x 17 k
      int r = s/17, k = s - r*17;
      As[k][r] = feats[(size_t)(row0+r)*204 + kc + k];
    }
    for (int s=t; s<2176; s+=256){         // Ws: 17 k x 128 j
      int k = s >> 7, j = s & 127;
      Ws[k][j] = Wr[(size_t)(kc+k)*128 + j];
    }
    __syncthreads();
    #pragma unroll
    for (int k=0;k<17;k++){
      float a[8], w[8];
      *(float4*)&a[0] = *(const float4*)&As[k][tr*4];
      *(float4*)&a[4] = *(const float4*)&As[k][64+tr*4];
      *(float4*)&w[0] = *(const float4*)&Ws[k][tc*4];
      *(float4*)&w[4] = *(const float4*)&Ws[k][64+tc*4];
      #pragma unroll
      for (int rg=0;rg<2;rg++)
        #pragma unroll
        for (int i=0;i<4;i++)
          #pragma unroll
          for (int cg=0;cg<2;cg++)
            #pragma unroll
            for (int j=0;j<4;j++)
              acc[rg][cg][i][j] += a[rg*4+i]*w[cg*4+j];
    }
    __syncthreads();
  }
  // cg=0: cols tc*4 (<64) -> zh ; cg=1: cols 64+tc*4 -> rbuf
  float bj0[4], bj1[4];
  #pragma unroll
  for (int j=0;j<4;j++){ bj0[j] = bias[tc*4+j]; bj1[j] = bias[64+tc*4+j]; }
  #pragma unroll
  for (int rg=0;rg<2;rg++){
    #pragma unroll
    for (int i=0;i<4;i++){
      int row = row0 + rg*64 + tr*4 + i;
      float4 h4 = *(const float4*)(hbuf + (size_t)row*64 + tc*4);
      float hv[4] = {h4.x,h4.y,h4.z,h4.w};
      float4 oz, orr;
      float z[4], rr[4];
      #pragma unroll
      for (int j=0;j<4;j++){
        z[j]  = 1.f/(1.f + __expf(-(acc[rg][0][i][j] + bj0[j])));
        rr[j] = 1.f/(1.f + __expf(-(acc[rg][1][i][j] + bj1[j])));
      }
      oz.x=z[0]*hv[0]; oz.y=z[1]*hv[1]; oz.z=z[2]*hv[2]; oz.w=z[3]*hv[3];
      orr.x=rr[0]; orr.y=rr[1]; orr.z=rr[2]; orr.w=rr[3];
      *(float4*)(zh   + (size_t)row*64 + tc*4) = oz;
      *(float4*)(rbuf + (size_t)row*64 + tc*4) = orr;
    }
  }
}

// Update: feats(204) @ Wr(204x64) -> tanh; h = r*h + (1-r)*hc  (in-place henc)
// Block 128 rows x 64 cols, TM8(4+4) x TN4.
__global__ __launch_bounds__(256) void k_gwU(
    const float* __restrict__ feats, const float* __restrict__ Wr,
    const float* __restrict__ bias,
    float* __restrict__ henc, const float* __restrict__ rbuf)
{
  __shared__ __align__(16) float As[17][132];
  __shared__ __align__(16) float Ws[17][68];
  const int t = threadIdx.x;
  const int row0 = blockIdx.x * 128;
  const int tr = t & 15, tc = t >> 4;
  float acc[2][4][4];
  #pragma unroll
  for (int rg=0;rg<2;rg++)
    #pragma unroll
    for (int i=0;i<4;i++)
      #pragma unroll
      for (int j=0;j<4;j++) acc[rg][i][j]=0.f;
  for (int kc=0; kc<204; kc+=17){
    for (int s=t; s<2176; s+=256){
      int r = s/17, k = s - r*17;
      As[k][r] = feats[(size_t)(row0+r)*204 + kc + k];
    }
    for (int s=t; s<1088; s+=256){         // Ws: 17 x 64
      int k = s >> 6, j = s & 63;
      Ws[k][j] = Wr[(size_t)(kc+k)*64 + j];
    }
    __syncthreads();
    #pragma unroll
    for (int k=0;k<17;k++){
      float a[8], w[4];
      *(float4*)&a[0] = *(const float4*)&As[k][tr*4];
      *(float4*)&a[4] = *(const float4*)&As[k][64+tr*4];
      *(float4*)&w[0] = *(const float4*)&Ws[k][tc*4];
      #pragma unroll
      for (int rg=0;rg<2;rg++)
        #pragma unroll
        for (int i=0;i<4;i++)
          #pragma unroll
          for (int j=0;j<4;j++)
            acc[rg][i][j] += a[rg*4+i]*w[j];
    }
    __syncthreads();
  }
  float bj[4];
  #pragma unroll
  for (int j=0;j<4;j++) bj[j] = bias[tc*4+j];
  #pragma unroll
  for (int rg=0;rg<2;rg++){
    #pragma unroll
    for (int i=0;i<4;i++){
      int row = row0 + rg*64 + tr*4 + i;
      float4 h4 = *(const float4*)(henc + (size_t)row*64 + tc*4);
      float4 r4 = *(const float4*)(rbuf + (size_t)row*64 + tc*4);
      float hv[4] = {h4.x,h4.y,h4.z,h4.w};
      float rv[4] = {r4.x,r4.y,r4.z,r4.w};
      float ov[4];
      #pragma unroll
      for (int j=0;j<4;j++){
        float hc = 1.f - 2.f/(__expf(2.f*(acc[rg][i][j] + bj[j])) + 1.f);
        ov[j] = rv[j]*hv[j] + (1.f - rv[j])*hc;
      }
      float4 o; o.x=ov[0]; o.y=ov[1]; o.z=ov[2]; o.w=ov[3];
      *(float4*)(henc + (size_t)row*64 + tc*4) = o;
    }
  }
}

// ======================= bf16 DECODER (R3 verbatim) =======================

__global__ void k_reorderB(const float* __restrict__ W, unsigned short* __restrict__ Wr,
                           int HC, int NEX, int C, int KP, int J){
  int idx = blockIdx.x*256 + threadIdx.x;
  if (idx >= J*KP) return;
  int j = idx / KP, kp = idx - j*KP;
  float v = 0.f;
  if (kp < 3*C){
    int seg = kp / C, c = kp - seg*C;
    int CIN = HC + NEX;
    if (c < HC)       v = W[(size_t)(seg*CIN + NEX + c)*J + j];
    else if (c < CIN) v = W[(size_t)(seg*CIN + (c-HC))*J + j];
  }
  Wr[(size_t)j*KP + kp] = f2b(v);
}

template<int C16, bool BETA>
__global__ __launch_bounds__(256) void k_mmB(
    const unsigned short* __restrict__ M, long long mstride,
    unsigned short* fC, int C3, int xseg, int oseg,
    unsigned short* fR, int KP, float alpha)
{
  constexpr int C = C16*16;
  constexpr int BIT = (C*4 + 255)/256;
  __shared__ unsigned short Bs[C*40];
  const int t = threadIdx.x;
  const int w = t >> 6, L = t & 63, lm = L & 15, q = L >> 4;
  const int bb = blockIdx.z;
  const int n0 = blockIdx.x * 128;
  const unsigned short* Mb = M + (size_t)bb * mstride;
  unsigned short* fCb = fC + (size_t)bb * C3 * 512;
  const unsigned short* Xb = fCb + (size_t)xseg * C * 512;
  const unsigned short* Yb = fCb;
  unsigned short* Ob = fCb + (size_t)oseg * C * 512;
  const int rw = n0 + w*32;

  f4v acc[2][C16];
  #pragma unroll
  for (int i=0;i<2;i++)
    #pragma unroll
    for (int j=0;j<C16;j++)
      #pragma unroll
      for (int r=0;r<4;r++) acc[i][j][r] = 0.f;

  s8v breg[BIT];
  const size_t ar0 = (size_t)(rw + lm)*512 + q*8;
  const size_t ar1 = (size_t)(rw + 16 + lm)*512 + q*8;

  #pragma unroll
  for (int i=0;i<BIT;i++){
    int s = t + i*256;
    if (s < C*4) breg[i] = *(const s8v*)(Xb + (size_t)(s>>2)*512 + (s&3)*8);
  }
  s8v a0 = *(const s8v*)(Mb + ar0);
  s8v a1 = *(const s8v*)(Mb + ar1);

  for (int ks=0; ks<16; ks++){
    #pragma unroll
    for (int i=0;i<BIT;i++){
      int s = t + i*256;
      if (s < C*4) *(s8v*)&Bs[(s>>2)*40 + (s&3)*8] = breg[i];
    }
    __syncthreads();
    const int kn = (ks < 15) ? (ks+1)*32 : 0;
    #pragma unroll
    for (int i=0;i<BIT;i++){
      int s = t + i*256;
      if (s < C*4) breg[i] = *(const s8v*)(Xb + (size_t)(s>>2)*512 + kn + (s&3)*8);
    }
    s8v a0n = *(const s8v*)(Mb + ar0 + kn);
    s8v a1n = *(const s8v*)(Mb + ar1 + kn);
    #pragma unroll
    for (int ct=0; ct<C16; ct++){
      s8v b = *(const s8v*)&Bs[(ct*16+lm)*40 + q*8];
      acc[0][ct] = __builtin_amdgcn_mfma_f32_16x16x32_bf16(a0, b, acc[0][ct], 0,0,0);
      acc[1][ct] = __builtin_amdgcn_mfma_f32_16x16x32_bf16(a1, b, acc[1][ct], 0,0,0);
    }
    __syncthreads();
    a0 = a0n; a1 = a1n;
  }
  #pragma unroll
  for (int rt=0; rt<2; rt++){
    const int m0 = rw + rt*16 + q*4;
    #pragma unroll
    for (int ct=0; ct<C16; ct++){
      const int c = ct*16 + lm;
      u4v o;
      if (BETA){
        u4v y = *(const u4v*)(Yb + (size_t)c*512 + m0);
        #pragma unroll
        for (int r=0;r<4;r++) o[r] = f2b(alpha*acc[rt][ct][r] - b2f(y[r]));
      } else {
        #pragma unroll
        for (int r=0;r<4;r++) o[r] = f2b(acc[rt][ct][r]);
      }
      *(u4v*)(Ob + (size_t)c*512 + m0) = o;
      const size_t rbase = (size_t)(bb*512 + m0)*KP + oseg*C + c;
      #pragma unroll
      for (int r=0;r<4;r++) fR[rbase + (size_t)r*KP] = o[r];
    }
  }
}

template<int KSTEPS, int JT16, int MODE, int HC>
__global__ __launch_bounds__(256) void k_gwB(
    unsigned short* fR, int KP,
    const unsigned short* __restrict__ Wr, const float* __restrict__ bias,
    unsigned short* fC, int C3,
    float* hC, float* rbuf)
{
  constexpr int JT = JT16*16;
  constexpr int BIT = JT*4/256;
  __shared__ unsigned short Bs[JT*40];
  const int t = threadIdx.x;
  const int w = t >> 6, L = t & 63, lm = L & 15, q = L >> 4;
  const int row0 = blockIdx.x * 128;
  const int j0 = blockIdx.y * JT;
  const int rw = row0 + w*32;

  f4v acc[2][JT16];
  #pragma unroll
  for (int i=0;i<2;i++)
    #pragma unroll
    for (int j=0;j<JT16;j++)
      #pragma unroll
      for (int r=0;r<4;r++) acc[i][j][r] = 0.f;

  s8v breg[BIT];
  const unsigned short* Wb = Wr + (size_t)j0*KP;
  const size_t ar0 = (size_t)(rw + lm)*KP + q*8;
  const size_t ar1 = (size_t)(rw + 16 + lm)*KP + q*8;

  #pragma unroll
  for (int i=0;i<BIT;i++){
    int s = t + i*256;
    breg[i] = *(const s8v*)(Wb + (size_t)(s>>2)*KP + (s&3)*8);
  }
  s8v a0 = *(const s8v*)(fR + ar0);
  s8v a1 = *(const s8v*)(fR + ar1);

  for (int ks=0; ks<KSTEPS; ks++){
    #pragma unroll
    for (int i=0;i<BIT;i++){
      int s = t + i*256;
      *(s8v*)&Bs[(s>>2)*40 + (s&3)*8] = breg[i];
    }
    __syncthreads();
    const int kn = (ks < KSTEPS-1) ? (ks+1)*32 : 0;
    #pragma unroll
    for (int i=0;i<BIT;i++){
      int s = t + i*256;
      breg[i] = *(const s8v*)(Wb + (size_t)(s>>2)*KP + kn + (s&3)*8);
    }
    s8v a0n = *(const s8v*)(fR + ar0 + kn);
    s8v a1n = *(const s8v*)(fR + ar1 + kn);
    #pragma unroll
    for (int ct=0; ct<JT16; ct++){
      s8v b = *(const s8v*)&Bs[(ct*16+lm)*40 + q*8];
      acc[0][ct] = __builtin_amdgcn_mfma_f32_16x16x32_bf16(a0, b, acc[0][ct], 0,0,0);
      acc[1][ct] = __builtin_amdgcn_mfma_f32_16x16x32_bf16(a1, b, acc[1][ct], 0,0,0);
    }
    __syncthreads();
    a0 = a0n; a1 = a1n;
  }
  #pragma unroll
  for (int rt=0; rt<2; rt++){
    const int m0 = rw + rt*16 + q*4;
    const int bb = m0 >> 9, n = m0 & 511;
    #pragma unroll
    for (int ct=0; ct<JT16; ct++){
      const int j = j0 + ct*16 + lm;
      const float bj = bias[j];
      if (MODE == 0){
        if (j < HC){
          f4v h4 = *(const f4v*)(hC + ((size_t)bb*HC + j)*512 + n);
          u4v o;
          #pragma unroll
          for (int r=0;r<4;r++){
            float s = 1.f/(1.f + __expf(-(acc[rt][ct][r] + bj)));
            float zh = s * h4[r];
            o[r] = f2b(zh);
            fR[(size_t)(m0+r)*KP + j] = o[r];
          }
          *(u4v*)(fC + ((size_t)bb*C3 + j)*512 + n) = o;
        } else {
          f4v rv;
          #pragma unroll
          for (int r=0;r<4;r++) rv[r] = 1.f/(1.f + __expf(-(acc[rt][ct][r] + bj)));
          *(f4v*)(rbuf + ((size_t)bb*HC + (j-HC))*512 + n) = rv;
        }
      } else {
        f4v h4 = *(const f4v*)(hC + ((size_t)bb*HC + j)*512 + n);
        f4v r4 = *(const f4v*)(rbuf + ((size_t)bb*HC + j)*512 + n);
        u4v o; f4v hn;
        #pragma unroll
        for (int r=0;r<4;r++){
          float e = __expf(2.f*(acc[rt][ct][r] + bj));
          float hc_ = 1.f - 2.f/(e + 1.f);
          hn[r] = r4[r]*h4[r] + (1.f - r4[r])*hc_;
          o[r] = f2b(hn[r]);
          fR[(size_t)(m0+r)*KP + j] = o[r];
        }
        *(f4v*)(hC + ((size_t)bb*HC + j)*512 + n) = hn;
        *(u4v*)(fC + ((size_t)bb*C3 + j)*512 + n) = o;
      }
    }
  }
}

// ======================= glue kernels =======================

__global__ void k_extras_dec(const float* __restrict__ yc,
    unsigned short* fR, unsigned short* fC, int tstep){
  int rr = blockIdx.x*256 + threadIdx.x;   // 32768
  int bb = rr >> 9, n = rr & 511;
  unsigned short u = f2b(yc[((size_t)bb*12 + tstep)*512 + n]);
  fR[(size_t)rr*448 + 129] = u;
  fC[((size_t)bb*432 + 129)*512 + n] = u;
}
__global__ void k_fix_go(unsigned short* fR, unsigned short* fC){
  int rr = blockIdx.x*256 + threadIdx.x;   // 32768
  int bb = rr >> 9, n = rr & 511;
  fR[(size_t)rr*448 + 128] = 0;
  fC[((size_t)bb*432 + 128)*512 + n] = 0;
}

__global__ __launch_bounds__(256) void k_query(const float* __restrict__ hR,
      const float* __restrict__ Wq, const float* __restrict__ Mem,
      float* __restrict__ hCd, unsigned short* fR, unsigned short* fC,
      int* __restrict__ it, int* __restrict__ ih){
  int sub = threadIdx.x >> 6, lane = threadIdx.x & 63;
  int row = blockIdx.x*4 + sub;          // 0..65535
  __shared__ float sh[4][64], sq[4][64], ss[4][20];
  float hv = hR[(size_t)row*64 + lane];
  sh[sub][lane] = hv;
  __syncthreads();
  float qv = 0.f;
  for (int c=0;c<64;c++) qv += sh[sub][c]*Wq[c*64 + lane];
  sq[sub][lane] = qv;
  __syncthreads();
  if (lane < 20){
    float s = 0.f;
    for (int j=0;j<64;j++) s += sq[sub][j]*Mem[lane*64 + j];
    ss[sub][lane] = s;
  }
  __syncthreads();
  float mx = -1e30f; int am = 0;
  for (int m=0;m<20;m++){ float s = ss[sub][m]; if (s > mx){ mx = s; am = m; } }
  float sum = 0.f;
  for (int m=0;m<20;m++) sum += __expf(ss[sub][m]-mx);
  float inv = 1.f/sum;
  float v = 0.f;
  for (int m=0;m<20;m++) v += __expf(ss[sub][m]-mx)*inv*Mem[m*64 + lane];
  int bb = row >> 9, n = row & 511;
  if (bb < 64){
    hCd[((size_t)bb*128 + lane)*512 + n] = hv;
    hCd[((size_t)bb*128 + 64 + lane)*512 + n] = v;
    fR[(size_t)row*448 + lane] = f2b(hv);
    fR[(size_t)row*448 + 64 + lane] = f2b(v);
    fC[((size_t)bb*432 + lane)*512 + n] = f2b(hv);
    fC[((size_t)bb*432 + 64 + lane)*512 + n] = f2b(v);
    if (lane==0) it[row] = am;
  } else {
    if (lane==0) ih[row - 32768] = am;
  }
}

__global__ void k_latent(const int* __restrict__ it, const int* __restrict__ ih,
                         const float* __restrict__ Mem,
                         const float* __restrict__ lW, const float* __restrict__ lb,
                         float* __restrict__ outl){
  int row = blockIdx.x*256 + threadIdx.x;  // 32768
  int i1 = it[row], i2 = ih[row];
  float a = lb[0];
  for (int c=0;c<64;c++) a += (Mem[i1*64+c]-Mem[i2*64+c])*lW[c];
  outl[row] = 1.f/(1.f + __expf(-a));
}

__global__ __launch_bounds__(256) void k_emb(const float* __restrict__ hCd,
    const float* __restrict__ hW, const float* __restrict__ hb, float* __restrict__ emb){
  __shared__ float sW[1280];
  int t = threadIdx.x;
  for (int s=t; s<1280; s+=256) sW[s] = hW[s];
  __syncthreads();
  int rr = blockIdx.x*256 + t;   // 32768
  int bb = rr >> 9, n = rr & 511;
  float a[10];
  #pragma unroll
  for (int e=0;e<10;e++) a[e] = hb[e];
  for (int c=0;c<128;c++){
    float v = hCd[((size_t)bb*128 + c)*512 + n];
    #pragma unroll
    for (int e=0;e<10;e++) a[e] += v*sW[c*10+e];
  }
  #pragma unroll
  for (int e=0;e<10;e++) emb[(size_t)rr*10 + e] = a[e];
}

__global__ __launch_bounds__(256) void k_support(const float* __restrict__ emb,
                                                 unsigned short* __restrict__ sup){
  int b = blockIdx.x >> 9;
  int n = blockIdx.x & 511;
  int t = threadIdx.x;
  __shared__ float se[5120];
  __shared__ float red[8];
  for (int s = t; s < 5120; s += 256) se[s] = emb[(size_t)b*5120 + s];
  __syncthreads();
  float en[10];
  #pragma unroll
  for (int i=0;i<10;i++) en[i] = se[n*10+i];
  float s0=0.f, s1=0.f;
  #pragma unroll
  for (int i=0;i<10;i++){ s0 += en[i]*se[t*10+i]; s1 += en[i]*se[(t+256)*10+i]; }
  s0 = fmaxf(s0, 0.f); s1 = fmaxf(s1, 0.f);
  float mx = fmaxf(s0, s1);
  for (int o=32;o>0;o>>=1) mx = fmaxf(mx, __shfl_down(mx, o));
  if ((t&63)==0) red[t>>6] = mx;
  __syncthreads();
  mx = fmaxf(fmaxf(red[0],red[1]), fmaxf(red[2],red[3]));
  float e0 = __expf(s0-mx), e1 = __expf(s1-mx);
  float sm = e0 + e1;
  for (int o=32;o>0;o>>=1) sm += __shfl_down(sm, o);
  if ((t&63)==0) red[4+(t>>6)] = sm;
  __syncthreads();
  sm = red[4]+red[5]+red[6]+red[7];
  float inv = 1.f/sm;
  size_t base = ((size_t)b*512 + n)*512;
  sup[base + t]       = f2b(e0*inv);
  sup[base + t + 256] = f2b(e1*inv);
}

__global__ __launch_bounds__(256) void k_proj(const float* __restrict__ hCd,
    const float* __restrict__ pW, const float* __restrict__ pb,
    unsigned short* fR, unsigned short* fC, float* __restrict__ out, int tstep){
  __shared__ float sW[128];
  int t = threadIdx.x;
  if (t < 128) sW[t] = pW[t];
  __syncthreads();
  int rr = blockIdx.x*256 + t;   // 32768
  int bb = rr >> 9, n = rr & 511;
  float a = pb[0];
  for (int c=0;c<128;c++) a += hCd[((size_t)bb*128 + c)*512 + n]*sW[c];
  out[((size_t)bb*12 + tstep)*512 + n] = a;
  unsigned short u = f2b(a);
  fR[(size_t)rr*448 + 128] = u;
  fC[((size_t)bb*432 + 128)*512 + n] = u;
}

extern "C" void kernel_launch(void* const* d_in, const int* in_sizes, int n_in,
                              void* d_out, int out_size, void* d_ws, size_t ws_size,
                              hipStream_t stream) {
  const float* x     = (const float*)d_in[0];
  const float* x_his = (const float*)d_in[2];
  const float* y_cov = (const float*)d_in[3];
  const float* adj   = (const float*)d_in[4];
  const float* egW   = (const float*)d_in[5];
  const float* egb   = (const float*)d_in[6];
  const float* euW   = (const float*)d_in[7];
  const float* eub   = (const float*)d_in[8];
  const float* dgW   = (const float*)d_in[9];
  const float* dgb   = (const float*)d_in[10];
  const float* duW   = (const float*)d_in[11];
  const float* dub   = (const float*)d_in[12];
  const float* Mem   = (const float*)d_in[13];
  const float* Wq    = (const float*)d_in[14];
  const float* hW    = (const float*)d_in[15];
  const float* hb    = (const float*)d_in[16];
  const float* lW    = (const float*)d_in[17];
  const float* lb    = (const float*)d_in[18];
  const float* pW    = (const float*)d_in[19];
  const float* pb    = (const float*)d_in[20];
  float* out  = (float*)d_out;           // (64,12,512,1)
  float* outl = out + 393216;            // (64,512)

  char* base = (char*)d_ws;
  size_t off = 0;
  auto alloc = [&](size_t bytes)->char*{
    char* p = base + off; off = (off + bytes + 255) & ~(size_t)255; return p;
  };
  float* featsF = (float*)alloc(53477376);       // 128*512*204 fp32 (encoder)
  //   decoder-phase aliases inside featsF (encoder feats dead by then):
  unsigned short* sup = (unsigned short*)featsF;            // 64*512*512 bf16
  float* emb = featsF + 8650752;                            // 32768*10 fp32
  int*   it  = (int*)(featsF + 9961472);                    // 32768
  int*   ih  = it + 32768;                                  // 32768
  float* henc = (float*)alloc(16777216);         // (128*512)x64 fp32, row-major
  float* zhF  = (float*)alloc(16777216);         // enc z*h (row-major); hCd alias
  float* hCd  = zhF;                             // (64,128,512) fp32 decoder state
  float* rbF  = (float*)alloc(16777216);         // enc r (row-major) / dec r (col-major)
  unsigned short* fR = (unsigned short*)alloc(29360128);  // 32768 x 448 bf16
  unsigned short* fC = (unsigned short*)alloc(28311552);  // 64 x 432 x 512 bf16
  float* a2e = (float*)alloc(1048576);           // 512x512 fp32
  float* wr_egF = (float*)alloc(104448);         // 204x128 fp32
  float* wr_euF = (float*)alloc(52224);          // 204x64 fp32
  unsigned short* wr_dg = (unsigned short*)alloc(229376); // 256x448 bf16
  unsigned short* wr_du = (unsigned short*)alloc(114688); // 128x448 bf16
  if (ws_size < off) return;

  // init (ws is re-poisoned every call)
  k_zero16<<<4096,256,0,stream>>>((uint4*)henc, 1048576);
  k_zero16<<<7168,256,0,stream>>>((uint4*)fR, 1835008);
  k_zero16<<<6912,256,0,stream>>>((uint4*)fC, 1769472);
  k_a2e<<<16,256,0,stream>>>(adj, a2e);
  k_reorderF<<<102,256,0,stream>>>(egW, wr_egF, 64,1,68,128);
  k_reorderF<<< 51,256,0,stream>>>(euW, wr_euF, 64,1,68,64);
  k_reorderB<<<448,256,0,stream>>>(dgW, wr_dg, 128,2,144,448,256);
  k_reorderB<<<224,256,0,stream>>>(duW, wr_du, 128,2,144,448,128);

  // ---------------- fp32 encoders: x | x_his paired per block ----------------
  for (int t = 0; t < 12; t++){
    k_mm2F<<<dim3(8,1,64),256,0,stream>>>(adj, a2e, henc, x, x_his, t, featsF);
    k_gwG<<<512,256,0,stream>>>(featsF, wr_egF, egb, henc, zhF, rbF);
    k_mm2F<<<dim3(8,1,64),256,0,stream>>>(adj, a2e, zhF, x, x_his, t, featsF);
    k_gwU<<<512,256,0,stream>>>(featsF, wr_euF, eub, henc, rbF);
  }

  // ---------------- memory query / latent / support (fp32 scores) ----------------
  k_query<<<16384,256,0,stream>>>(henc, Wq, Mem, hCd, fR, fC, it, ih);
  k_latent<<<128,256,0,stream>>>(it, ih, Mem, lW, lb, outl);
  k_emb<<<128,256,0,stream>>>(hCd, hW, hb, emb);
  k_support<<<32768,256,0,stream>>>(emb, sup);
  k_fix_go<<<128,256,0,stream>>>(fR, fC);

  // ---------------- bf16 decoder, BB=64 ----------------
  for (int t = 0; t < 12; t++){
    k_extras_dec<<<128,256,0,stream>>>(y_cov, fR, fC, t);
    k_mmB<9,false><<<dim3(4,1,64),256,0,stream>>>(sup, 262144, fC, 432, 0, 1, fR, 448, 1.f);
    k_mmB<9,true ><<<dim3(4,1,64),256,0,stream>>>(sup, 262144, fC, 432, 1, 2, fR, 448, 2.f);
    k_gwB<14,16,0,128><<<dim3(256,1),256,0,stream>>>(fR, 448, wr_dg, dgb, fC, 432, hCd, rbF);
    k_mmB<9,false><<<dim3(4,1,64),256,0,stream>>>(sup, 262144, fC, 432, 0, 1, fR, 448, 1.f);
    k_mmB<9,true ><<<dim3(4,1,64),256,0,stream>>>(sup, 262144, fC, 432, 1, 2, fR, 448, 2.f);
    k_gwB<14,8,1,128><<<dim3(256,1),256,0,stream>>>(fR, 448, wr_du, dub, fC, 432, hCd, rbF);
    k_proj<<<128,256,0,stream>>>(hCd, pW, pb, fR, fC, out, t);
  }
}

// Round 9
// 6503.373 us; speedup vs baseline: 1.1231x; 1.1231x over previous
//
#include <hip/hip_runtime.h>
#include <hip/hip_bf16.h>

// MDGCRN hybrid: fp32 encoder (argmax-exact path) + bf16-MFMA decoder.
// R9: encoder half-step FULLY FUSED (k_enc<MODE>): graph-conv (R8's k_mm2F
//     body, bit-exact) + feats@W + GRU epilogue in one kernel. The fp32
//     feats array (58 MB write + re-read per half-step) is eliminated —
//     G0/G1/G2 live in LDS/registers. Decoder = R3.

typedef __attribute__((ext_vector_type(8))) short s8v;
typedef __attribute__((ext_vector_type(4))) float f4v;
typedef __attribute__((ext_vector_type(4))) unsigned short u4v;

__device__ __forceinline__ float b2f(unsigned short u){
  union{unsigned int i; float f;} v; v.i = ((unsigned int)u)<<16; return v.f;
}
__device__ __forceinline__ unsigned short f2b(float f){
  union{float f; unsigned int i;} v; v.f = f;
  unsigned int r = v.i + 0x7fff + ((v.i >> 16) & 1);   // RNE (finite inputs only)
  return (unsigned short)(r >> 16);
}

__global__ void k_zero16(uint4* p, int n){
  int i = blockIdx.x*256 + threadIdx.x;
  if (i < n) p[i] = make_uint4(0,0,0,0);
}

// ======================= fp32 ENCODER =======================

__global__ void k_reorderF(const float* __restrict__ W, float* __restrict__ Wr,
                           int HC, int NEX, int SEGW, int J){
  int idx = blockIdx.x*256 + threadIdx.x;
  int K = 3*SEGW;
  if (idx >= K*J) return;
  int k = idx / J, j = idx - k*J;
  int seg = k / SEGW, c = k - seg*SEGW;
  int CIN = HC + NEX;
  float v = 0.f;
  if (c < HC)       v = W[(size_t)(seg*CIN + NEX + c)*J + j];
  else if (c < CIN) v = W[(size_t)(seg*CIN + (c-HC))*J + j];
  Wr[(size_t)k*J + j] = v;
}

// A2e = 2*A@A - I   (512x512)
__global__ __launch_bounds__(256) void k_a2e(const float* __restrict__ A,
                                             float* __restrict__ A2e){
  __shared__ __align__(16) float As[32][132];
  __shared__ __align__(16) float Bs[32][132];
  int t = threadIdx.x;
  int r0 = (blockIdx.x & 3) * 128;
  int c0 = (blockIdx.x >> 2) * 128;
  int tr = t & 15, tc = t >> 4;
  float acc[8][8];
  #pragma unroll
  for (int i=0;i<8;i++)
    #pragma unroll
    for (int j=0;j<8;j++) acc[i][j]=0.f;
  for (int k0=0;k0<512;k0+=32){
    #pragma unroll
    for (int i=0;i<4;i++){
      int s = t + i*256;
      int k = s & 31, rq = s >> 5;
      const float* ap = A + (size_t)(r0 + rq*4)*512 + k0 + k;
      float4 v;
      v.x = ap[0]; v.y = ap[512]; v.z = ap[1024]; v.w = ap[1536];
      *(float4*)&As[k][rq*4] = v;
    }
    #pragma unroll
    for (int i=0;i<4;i++){
      int s = t + i*256;
      int k = s >> 5, cq = s & 31;
      float4 v = *(const float4*)(A + (size_t)(k0+k)*512 + c0 + cq*4);
      *(float4*)&Bs[k][cq*4] = v;
    }
    __syncthreads();
    #pragma unroll 8
    for (int k=0;k<32;k++){
      float a[8], b[8];
      *(float4*)&a[0] = *(const float4*)&As[k][tr*4];
      *(float4*)&a[4] = *(const float4*)&As[k][64+tr*4];
      *(float4*)&b[0] = *(const float4*)&Bs[k][tc*4];
      *(float4*)&b[4] = *(const float4*)&Bs[k][64+tc*4];
      #pragma unroll
      for (int i=0;i<8;i++)
        #pragma unroll
        for (int j=0;j<8;j++) acc[i][j] += a[i]*b[j];
    }
    __syncthreads();
  }
  #pragma unroll
  for (int i=0;i<8;i++){
    int r = r0 + (i<4 ? tr*4+i : 64+tr*4+i-4);
    #pragma unroll
    for (int j=0;j<8;j++){
      int c = c0 + (j<4 ? tc*4+j : 64+tc*4+j-4);
      A2e[(size_t)r*512 + c] = 2.f*acc[i][j] - (r==c ? 1.f : 0.f);
    }
  }
}

// Fused encoder half-step: conv (G1=A@G0, G2=A2e@G0, G0=[hsrc|x]) for pair
// bb=z, z+64 + feats@W + GRU epilogue. No global feats.
// MODE 0 (gate): sigmoid; j<64 -> zh=s*h (h from F0t), j>=64 -> rbuf=s.
// MODE 1 (upd):  tanh; hnew = r*henc + (1-r)*hc -> henc in-place.
// Grid dim3(64,1,8): x=pair (XCD-affine for G0 L2-reuse), z=rowblk. 256 thr.
template<int MODE>
__global__ __launch_bounds__(256) void k_enc(
    const float* __restrict__ A, const float* __restrict__ A2e,
    const float* __restrict__ hsrc,             // [row][64] row-major
    const float* __restrict__ xa, const float* __restrict__ xb,  // (64,12,512)
    int tstep, const float* __restrict__ Wr, const float* __restrict__ bias,
    float* __restrict__ zh, float* __restrict__ rbuf, float* __restrict__ henc)
{
  constexpr int J  = (MODE==0) ? 128 : 64;
  constexpr int TN = (MODE==0) ? 8 : 4;
  __shared__ __align__(16) float R1[8704];        // phase1 staging / phase2 G12s
  __shared__ __align__(16) float F0t[2][65][66];  // G0 own rows, transposed [c][r]
  float (*sA)[68]   = (float(*)[68])(R1);
  float (*sA2)[68]  = (float(*)[68])(R1 + 2176);
  float (*sB0)[68]  = (float(*)[68])(R1 + 4352);
  float (*sB1)[68]  = (float(*)[68])(R1 + 6528);
  float (*G12s)[66] = (float(*)[66])(R1);         // [130][66]: G1 c0..64, G2 65..129
  const int t = threadIdx.x;
  const int z = blockIdx.x;                       // pair: bb0=z, bb1=z+64
  const int rowblk = blockIdx.z;
  const int n0 = rowblk * 64;
  const int tr = t & 15, tc = t >> 4;
  const int xrow = t & 63, xmat = (t >> 6) & 1, xbb = t >> 7;
  const float* xp0 = xa + ((size_t)z*12 + tstep)*512;
  const float* xp1 = xb + ((size_t)z*12 + tstep)*512;

  float acc[2][2][4][4];                          // [mat][bb][i][j]
  #pragma unroll
  for (int m=0;m<2;m++)
    #pragma unroll
    for (int b=0;b<2;b++)
      #pragma unroll
      for (int i=0;i<4;i++)
        #pragma unroll
        for (int j=0;j<4;j++) acc[m][b][i][j]=0.f;
  float xacc = 0.f;

  // ---- phase 1: dual conv (bit-exact R8 k_mm2F body) ----
  for (int k0=0;k0<512;k0+=32){
    #pragma unroll
    for (int i=0;i<2;i++){
      int s = t + i*256;
      int k = s & 31, rq = s >> 5;
      const float* ap  = A   + (size_t)(n0 + rq*4)*512 + k0 + k;
      const float* a2p = A2e + (size_t)(n0 + rq*4)*512 + k0 + k;
      float4 v, w;
      v.x = ap[0];  v.y = ap[512];  v.z = ap[1024];  v.w = ap[1536];
      w.x = a2p[0]; w.y = a2p[512]; w.z = a2p[1024]; w.w = a2p[1536];
      *(float4*)&sA[k][rq*4]  = v;
      *(float4*)&sA2[k][rq*4] = w;
    }
    #pragma unroll
    for (int i=0;i<2;i++){
      int s = t + i*256;
      int k = s >> 4, cq = s & 15;
      *(float4*)&sB0[k][cq*4] = *(const float4*)(hsrc + (size_t)(z*512 + k0 + k)*64 + cq*4);
      *(float4*)&sB1[k][cq*4] = *(const float4*)(hsrc + (size_t)((z+64)*512 + k0 + k)*64 + cq*4);
    }
    if (t < 32)      sB0[t][64]    = xp0[k0 + t];
    else if (t < 64) sB1[t-32][64] = xp1[k0 + t - 32];
    __syncthreads();
    #pragma unroll 4
    for (int k=0;k<32;k++){
      float a1[4], a2[4], b0[4], b1[4];
      *(float4*)&a1[0] = *(const float4*)&sA[k][tr*4];
      *(float4*)&a2[0] = *(const float4*)&sA2[k][tr*4];
      *(float4*)&b0[0] = *(const float4*)&sB0[k][tc*4];
      *(float4*)&b1[0] = *(const float4*)&sB1[k][tc*4];
      #pragma unroll
      for (int i=0;i<4;i++)
        #pragma unroll
        for (int j=0;j<4;j++){
          acc[0][0][i][j] += a1[i]*b0[j];
          acc[0][1][i][j] += a1[i]*b1[j];
          acc[1][0][i][j] += a2[i]*b0[j];
          acc[1][1][i][j] += a2[i]*b1[j];
        }
      float am = xmat ? sA2[k][xrow] : sA[k][xrow];
      xacc += am * (xbb ? sB1[k][64] : sB0[k][64]);
    }
    // own-rows G0 -> F0t (transposed), replaces global seg0 writeback
    if ((k0 >> 6) == rowblk){
      const int off = k0 & 63;                    // 0 or 32
      for (int s=t; s<4160; s+=256){              // 2 bb x 65 c x 32 rows
        int sb = (s >= 2080) ? 1 : 0;
        int ss = s - sb*2080;
        int c = ss >> 5, kk = ss & 31;
        F0t[sb][c][off + kk] = sb ? sB1[kk][c] : sB0[kk][c];
      }
    }
    __syncthreads();
  }

  // ---- phase 2: per bb, G1/G2 -> LDS, then [G0|G1|G2]@W + epilogue ----
  for (int bbi=0; bbi<2; bbi++){
    #pragma unroll
    for (int m=0;m<2;m++)
      #pragma unroll
      for (int j=0;j<4;j++){
        float4 v;
        v.x = acc[m][bbi][0][j]; v.y = acc[m][bbi][1][j];
        v.z = acc[m][bbi][2][j]; v.w = acc[m][bbi][3][j];
        *(float4*)&G12s[m*65 + tc*4 + j][tr*4] = v;
      }
    if (xbb == bbi) G12s[xmat*65 + 64][xrow] = xacc;
    __syncthreads();

    float acc2[4][TN];
    #pragma unroll
    for (int i=0;i<4;i++)
      #pragma unroll
      for (int jj=0;jj<TN;jj++) acc2[i][jj]=0.f;
    const int j0 = tc*TN;

    #pragma unroll 4
    for (int c=0;c<65;c++){                       // seg0: W rows 0..64
      float a[4], w[TN];
      *(float4*)&a[0] = *(const float4*)&F0t[bbi][c][tr*4];
      #pragma unroll
      for (int q=0;q<TN;q+=4) *(float4*)&w[q] = *(const float4*)(Wr + (size_t)c*J + j0 + q);
      #pragma unroll
      for (int i=0;i<4;i++)
        #pragma unroll
        for (int jj=0;jj<TN;jj++) acc2[i][jj] += a[i]*w[jj];
    }
    #pragma unroll 4
    for (int c=0;c<65;c++){                       // G1: W rows 68..132
      float a[4], w[TN];
      *(float4*)&a[0] = *(const float4*)&G12s[c][tr*4];
      #pragma unroll
      for (int q=0;q<TN;q+=4) *(float4*)&w[q] = *(const float4*)(Wr + (size_t)(68+c)*J + j0 + q);
      #pragma unroll
      for (int i=0;i<4;i++)
        #pragma unroll
        for (int jj=0;jj<TN;jj++) acc2[i][jj] += a[i]*w[jj];
    }
    #pragma unroll 4
    for (int c=0;c<65;c++){                       // G2: W rows 136..200
      float a[4], w[TN];
      *(float4*)&a[0] = *(const float4*)&G12s[65+c][tr*4];
      #pragma unroll
      for (int q=0;q<TN;q+=4) *(float4*)&w[q] = *(const float4*)(Wr + (size_t)(136+c)*J + j0 + q);
      #pragma unroll
      for (int i=0;i<4;i++)
        #pragma unroll
        for (int jj=0;jj<TN;jj++) acc2[i][jj] += a[i]*w[jj];
    }

    float bj[TN];
    #pragma unroll
    for (int jj=0;jj<TN;jj++) bj[jj] = bias[j0+jj];
    const int gbase = (z + bbi*64)*512 + n0;
    #pragma unroll
    for (int i=0;i<4;i++){
      const int lr = tr*4 + i;
      const int row = gbase + lr;
      if (MODE == 0){
        float s[8];
        #pragma unroll
        for (int jj=0;jj<TN;jj++) s[jj] = 1.f/(1.f + __expf(-(acc2[i][jj] + bj[jj])));
        if (j0 < 64){
          float4 o0, o1;
          o0.x = s[0]*F0t[bbi][j0+0][lr]; o0.y = s[1]*F0t[bbi][j0+1][lr];
          o0.z = s[2]*F0t[bbi][j0+2][lr]; o0.w = s[3]*F0t[bbi][j0+3][lr];
          o1.x = s[4]*F0t[bbi][j0+4][lr]; o1.y = s[5]*F0t[bbi][j0+5][lr];
          o1.z = s[6]*F0t[bbi][j0+6][lr]; o1.w = s[7]*F0t[bbi][j0+7][lr];
          *(float4*)(zh + (size_t)row*64 + j0)     = o0;
          *(float4*)(zh + (size_t)row*64 + j0 + 4) = o1;
        } else {
          float4 o0, o1;
          o0.x=s[0]; o0.y=s[1]; o0.z=s[2]; o0.w=s[3];
          o1.x=s[4]; o1.y=s[5]; o1.z=s[6]; o1.w=s[7];
          *(float4*)(rbuf + (size_t)row*64 + j0 - 64) = o0;
          *(float4*)(rbuf + (size_t)row*64 + j0 - 60) = o1;
        }
      } else {
        float4 h4 = *(const float4*)(henc + (size_t)row*64 + j0);
        float4 r4 = *(const float4*)(rbuf + (size_t)row*64 + j0);
        float hv[4] = {h4.x,h4.y,h4.z,h4.w};
        float rv[4] = {r4.x,r4.y,r4.z,r4.w};
        float ov[4];
        #pragma unroll
        for (int jj=0;jj<4;jj++){
          float hc = 1.f - 2.f/(__expf(2.f*(acc2[i][jj] + bj[jj])) + 1.f);
          ov[jj] = rv[jj]*hv[jj] + (1.f - rv[jj])*hc;
        }
        float4 o; o.x=ov[0]; o.y=ov[1]; o.z=ov[2]; o.w=ov[3];
        *(float4*)(henc + (size_t)row*64 + j0) = o;
      }
    }
    __syncthreads();
  }
}

// ======================= bf16 DECODER (R3 verbatim) =======================

__global__ void k_reorderB(const float* __restrict__ W, unsigned short* __restrict__ Wr,
                           int HC, int NEX, int C, int KP, int J){
  int idx = blockIdx.x*256 + threadIdx.x;
  if (idx >= J*KP) return;
  int j = idx / KP, kp = idx - j*KP;
  float v = 0.f;
  if (kp < 3*C){
    int seg = kp / C, c = kp - seg*C;
    int CIN = HC + NEX;
    if (c < HC)       v = W[(size_t)(seg*CIN + NEX + c)*J + j];
    else if (c < CIN) v = W[(size_t)(seg*CIN + (c-HC))*J + j];
  }
  Wr[(size_t)j*KP + kp] = f2b(v);
}

template<int C16, bool BETA>
__global__ __launch_bounds__(256) void k_mmB(
    const unsigned short* __restrict__ M, long long mstride,
    unsigned short* fC, int C3, int xseg, int oseg,
    unsigned short* fR, int KP, float alpha)
{
  constexpr int C = C16*16;
  constexpr int BIT = (C*4 + 255)/256;
  __shared__ unsigned short Bs[C*40];
  const int t = threadIdx.x;
  const int w = t >> 6, L = t & 63, lm = L & 15, q = L >> 4;
  const int bb = blockIdx.z;
  const int n0 = blockIdx.x * 128;
  const unsigned short* Mb = M + (size_t)bb * mstride;
  unsigned short* fCb = fC + (size_t)bb * C3 * 512;
  const unsigned short* Xb = fCb + (size_t)xseg * C * 512;
  const unsigned short* Yb = fCb;
  unsigned short* Ob = fCb + (size_t)oseg * C * 512;
  const int rw = n0 + w*32;

  f4v acc[2][C16];
  #pragma unroll
  for (int i=0;i<2;i++)
    #pragma unroll
    for (int j=0;j<C16;j++)
      #pragma unroll
      for (int r=0;r<4;r++) acc[i][j][r] = 0.f;

  s8v breg[BIT];
  const size_t ar0 = (size_t)(rw + lm)*512 + q*8;
  const size_t ar1 = (size_t)(rw + 16 + lm)*512 + q*8;

  #pragma unroll
  for (int i=0;i<BIT;i++){
    int s = t + i*256;
    if (s < C*4) breg[i] = *(const s8v*)(Xb + (size_t)(s>>2)*512 + (s&3)*8);
  }
  s8v a0 = *(const s8v*)(Mb + ar0);
  s8v a1 = *(const s8v*)(Mb + ar1);

  for (int ks=0; ks<16; ks++){
    #pragma unroll
    for (int i=0;i<BIT;i++){
      int s = t + i*256;
      if (s < C*4) *(s8v*)&Bs[(s>>2)*40 + (s&3)*8] = breg[i];
    }
    __syncthreads();
    const int kn = (ks < 15) ? (ks+1)*32 : 0;
    #pragma unroll
    for (int i=0;i<BIT;i++){
      int s = t + i*256;
      if (s < C*4) breg[i] = *(const s8v*)(Xb + (size_t)(s>>2)*512 + kn + (s&3)*8);
    }
    s8v a0n = *(const s8v*)(Mb + ar0 + kn);
    s8v a1n = *(const s8v*)(Mb + ar1 + kn);
    #pragma unroll
    for (int ct=0; ct<C16; ct++){
      s8v b = *(const s8v*)&Bs[(ct*16+lm)*40 + q*8];
      acc[0][ct] = __builtin_amdgcn_mfma_f32_16x16x32_bf16(a0, b, acc[0][ct], 0,0,0);
      acc[1][ct] = __builtin_amdgcn_mfma_f32_16x16x32_bf16(a1, b, acc[1][ct], 0,0,0);
    }
    __syncthreads();
    a0 = a0n; a1 = a1n;
  }
  #pragma unroll
  for (int rt=0; rt<2; rt++){
    const int m0 = rw + rt*16 + q*4;
    #pragma unroll
    for (int ct=0; ct<C16; ct++){
      const int c = ct*16 + lm;
      u4v o;
      if (BETA){
        u4v y = *(const u4v*)(Yb + (size_t)c*512 + m0);
        #pragma unroll
        for (int r=0;r<4;r++) o[r] = f2b(alpha*acc[rt][ct][r] - b2f(y[r]));
      } else {
        #pragma unroll
        for (int r=0;r<4;r++) o[r] = f2b(acc[rt][ct][r]);
      }
      *(u4v*)(Ob + (size_t)c*512 + m0) = o;
      const size_t rbase = (size_t)(bb*512 + m0)*KP + oseg*C + c;
      #pragma unroll
      for (int r=0;r<4;r++) fR[rbase + (size_t)r*KP] = o[r];
    }
  }
}

template<int KSTEPS, int JT16, int MODE, int HC>
__global__ __launch_bounds__(256) void k_gwB(
    unsigned short* fR, int KP,
    const unsigned short* __restrict__ Wr, const float* __restrict__ bias,
    unsigned short* fC, int C3,
    float* hC, float* rbuf)
{
  constexpr int JT = JT16*16;
  constexpr int BIT = JT*4/256;
  __shared__ unsigned short Bs[JT*40];
  const int t = threadIdx.x;
  const int w = t >> 6, L = t & 63, lm = L & 15, q = L >> 4;
  const int row0 = blockIdx.x * 128;
  const int j0 = blockIdx.y * JT;
  const int rw = row0 + w*32;

  f4v acc[2][JT16];
  #pragma unroll
  for (int i=0;i<2;i++)
    #pragma unroll
    for (int j=0;j<JT16;j++)
      #pragma unroll
      for (int r=0;r<4;r++) acc[i][j][r] = 0.f;

  s8v breg[BIT];
  const unsigned short* Wb = Wr + (size_t)j0*KP;
  const size_t ar0 = (size_t)(rw + lm)*KP + q*8;
  const size_t ar1 = (size_t)(rw + 16 + lm)*KP + q*8;

  #pragma unroll
  for (int i=0;i<BIT;i++){
    int s = t + i*256;
    breg[i] = *(const s8v*)(Wb + (size_t)(s>>2)*KP + (s&3)*8);
  }
  s8v a0 = *(const s8v*)(fR + ar0);
  s8v a1 = *(const s8v*)(fR + ar1);

  for (int ks=0; ks<KSTEPS; ks++){
    #pragma unroll
    for (int i=0;i<BIT;i++){
      int s = t + i*256;
      *(s8v*)&Bs[(s>>2)*40 + (s&3)*8] = breg[i];
    }
    __syncthreads();
    const int kn = (ks < KSTEPS-1) ? (ks+1)*32 : 0;
    #pragma unroll
    for (int i=0;i<BIT;i++){
      int s = t + i*256;
      breg[i] = *(const s8v*)(Wb + (size_t)(s>>2)*KP + kn + (s&3)*8);
    }
    s8v a0n = *(const s8v*)(fR + ar0 + kn);
    s8v a1n = *(const s8v*)(fR + ar1 + kn);
    #pragma unroll
    for (int ct=0; ct<JT16; ct++){
      s8v b = *(const s8v*)&Bs[(ct*16+lm)*40 + q*8];
      acc[0][ct] = __builtin_amdgcn_mfma_f32_16x16x32_bf16(a0, b, acc[0][ct], 0,0,0);
      acc[1][ct] = __builtin_amdgcn_mfma_f32_16x16x32_bf16(a1, b, acc[1][ct], 0,0,0);
    }
    __syncthreads();
    a0 = a0n; a1 = a1n;
  }
  #pragma unroll
  for (int rt=0; rt<2; rt++){
    const int m0 = rw + rt*16 + q*4;
    const int bb = m0 >> 9, n = m0 & 511;
    #pragma unroll
    for (int ct=0; ct<JT16; ct++){
      const int j = j0 + ct*16 + lm;
      const float bj = bias[j];
      if (MODE == 0){
        if (j < HC){
          f4v h4 = *(const f4v*)(hC + ((size_t)bb*HC + j)*512 + n);
          u4v o;
          #pragma unroll
          for (int r=0;r<4;r++){
            float s = 1.f/(1.f + __expf(-(acc[rt][ct][r] + bj)));
            float zh = s * h4[r];
            o[r] = f2b(zh);
            fR[(size_t)(m0+r)*KP + j] = o[r];
          }
          *(u4v*)(fC + ((size_t)bb*C3 + j)*512 + n) = o;
        } else {
          f4v rv;
          #pragma unroll
          for (int r=0;r<4;r++) rv[r] = 1.f/(1.f + __expf(-(acc[rt][ct][r] + bj)));
          *(f4v*)(rbuf + ((size_t)bb*HC + (j-HC))*512 + n) = rv;
        }
      } else {
        f4v h4 = *(const f4v*)(hC + ((size_t)bb*HC + j)*512 + n);
        f4v r4 = *(const f4v*)(rbuf + ((size_t)bb*HC + j)*512 + n);
        u4v o; f4v hn;
        #pragma unroll
        for (int r=0;r<4;r++){
          float e = __expf(2.f*(acc[rt][ct][r] + bj));
          float hc_ = 1.f - 2.f/(e + 1.f);
          hn[r] = r4[r]*h4[r] + (1.f - r4[r])*hc_;
          o[r] = f2b(hn[r]);
          fR[(size_t)(m0+r)*KP + j] = o[r];
        }
        *(f4v*)(hC + ((size_t)bb*HC + j)*512 + n) = hn;
        *(u4v*)(fC + ((size_t)bb*C3 + j)*512 + n) = o;
      }
    }
  }
}

// ======================= glue kernels =======================

__global__ void k_extras_dec(const float* __restrict__ yc,
    unsigned short* fR, unsigned short* fC, int tstep){
  int rr = blockIdx.x*256 + threadIdx.x;   // 32768
  int bb = rr >> 9, n = rr & 511;
  unsigned short u = f2b(yc[((size_t)bb*12 + tstep)*512 + n]);
  fR[(size_t)rr*448 + 129] = u;
  fC[((size_t)bb*432 + 129)*512 + n] = u;
}
__global__ void k_fix_go(unsigned short* fR, unsigned short* fC){
  int rr = blockIdx.x*256 + threadIdx.x;   // 32768
  int bb = rr >> 9, n = rr & 511;
  fR[(size_t)rr*448 + 128] = 0;
  fC[((size_t)bb*432 + 128)*512 + n] = 0;
}

__global__ __launch_bounds__(256) void k_query(const float* __restrict__ hR,
      const float* __restrict__ Wq, const float* __restrict__ Mem,
      float* __restrict__ hCd, unsigned short* fR, unsigned short* fC,
      int* __restrict__ it, int* __restrict__ ih){
  int sub = threadIdx.x >> 6, lane = threadIdx.x & 63;
  int row = blockIdx.x*4 + sub;          // 0..65535
  __shared__ float sh[4][64], sq[4][64], ss[4][20];
  float hv = hR[(size_t)row*64 + lane];
  sh[sub][lane] = hv;
  __syncthreads();
  float qv = 0.f;
  for (int c=0;c<64;c++) qv += sh[sub][c]*Wq[c*64 + lane];
  sq[sub][lane] = qv;
  __syncthreads();
  if (lane < 20){
    float s = 0.f;
    for (int j=0;j<64;j++) s += sq[sub][j]*Mem[lane*64 + j];
    ss[sub][lane] = s;
  }
  __syncthreads();
  float mx = -1e30f; int am = 0;
  for (int m=0;m<20;m++){ float s = ss[sub][m]; if (s > mx){ mx = s; am = m; } }
  float sum = 0.f;
  for (int m=0;m<20;m++) sum += __expf(ss[sub][m]-mx);
  float inv = 1.f/sum;
  float v = 0.f;
  for (int m=0;m<20;m++) v += __expf(ss[sub][m]-mx)*inv*Mem[m*64 + lane];
  int bb = row >> 9, n = row & 511;
  if (bb < 64){
    hCd[((size_t)bb*128 + lane)*512 + n] = hv;
    hCd[((size_t)bb*128 + 64 + lane)*512 + n] = v;
    fR[(size_t)row*448 + lane] = f2b(hv);
    fR[(size_t)row*448 + 64 + lane] = f2b(v);
    fC[((size_t)bb*432 + lane)*512 + n] = f2b(hv);
    fC[((size_t)bb*432 + 64 + lane)*512 + n] = f2b(v);
    if (lane==0) it[row] = am;
  } else {
    if (lane==0) ih[row - 32768] = am;
  }
}

__global__ void k_latent(const int* __restrict__ it, const int* __restrict__ ih,
                         const float* __restrict__ Mem,
                         const float* __restrict__ lW, const float* __restrict__ lb,
                         float* __restrict__ outl){
  int row = blockIdx.x*256 + threadIdx.x;  // 32768
  int i1 = it[row], i2 = ih[row];
  float a = lb[0];
  for (int c=0;c<64;c++) a += (Mem[i1*64+c]-Mem[i2*64+c])*lW[c];
  outl[row] = 1.f/(1.f + __expf(-a));
}

__global__ __launch_bounds__(256) void k_emb(const float* __restrict__ hCd,
    const float* __restrict__ hW, const float* __restrict__ hb, float* __restrict__ emb){
  __shared__ float sW[1280];
  int t = threadIdx.x;
  for (int s=t; s<1280; s+=256) sW[s] = hW[s];
  __syncthreads();
  int rr = blockIdx.x*256 + t;   // 32768
  int bb = rr >> 9, n = rr & 511;
  float a[10];
  #pragma unroll
  for (int e=0;e<10;e++) a[e] = hb[e];
  for (int c=0;c<128;c++){
    float v = hCd[((size_t)bb*128 + c)*512 + n];
    #pragma unroll
    for (int e=0;e<10;e++) a[e] += v*sW[c*10+e];
  }
  #pragma unroll
  for (int e=0;e<10;e++) emb[(size_t)rr*10 + e] = a[e];
}

__global__ __launch_bounds__(256) void k_support(const float* __restrict__ emb,
                                                 unsigned short* __restrict__ sup){
  int b = blockIdx.x >> 9;
  int n = blockIdx.x & 511;
  int t = threadIdx.x;
  __shared__ float se[5120];
  __shared__ float red[8];
  for (int s = t; s < 5120; s += 256) se[s] = emb[(size_t)b*5120 + s];
  __syncthreads();
  float en[10];
  #pragma unroll
  for (int i=0;i<10;i++) en[i] = se[n*10+i];
  float s0=0.f, s1=0.f;
  #pragma unroll
  for (int i=0;i<10;i++){ s0 += en[i]*se[t*10+i]; s1 += en[i]*se[(t+256)*10+i]; }
  s0 = fmaxf(s0, 0.f); s1 = fmaxf(s1, 0.f);
  float mx = fmaxf(s0, s1);
  for (int o=32;o>0;o>>=1) mx = fmaxf(mx, __shfl_down(mx, o));
  if ((t&63)==0) red[t>>6] = mx;
  __syncthreads();
  mx = fmaxf(fmaxf(red[0],red[1]), fmaxf(red[2],red[3]));
  float e0 = __expf(s0-mx), e1 = __expf(s1-mx);
  float sm = e0 + e1;
  for (int o=32;o>0;o>>=1) sm += __shfl_down(sm, o);
  if ((t&63)==0) red[4+(t>>6)] = sm;
  __syncthreads();
  sm = red[4]+red[5]+red[6]+red[7];
  float inv = 1.f/sm;
  size_t base = ((size_t)b*512 + n)*512;
  sup[base + t]       = f2b(e0*inv);
  sup[base + t + 256] = f2b(e1*inv);
}

__global__ __launch_bounds__(256) void k_proj(const float* __restrict__ hCd,
    const float* __restrict__ pW, const float* __restrict__ pb,
    unsigned short* fR, unsigned short* fC, float* __restrict__ out, int tstep){
  __shared__ float sW[128];
  int t = threadIdx.x;
  if (t < 128) sW[t] = pW[t];
  __syncthreads();
  int rr = blockIdx.x*256 + t;   // 32768
  int bb = rr >> 9, n = rr & 511;
  float a = pb[0];
  for (int c=0;c<128;c++) a += hCd[((size_t)bb*128 + c)*512 + n]*sW[c];
  out[((size_t)bb*12 + tstep)*512 + n] = a;
  unsigned short u = f2b(a);
  fR[(size_t)rr*448 + 128] = u;
  fC[((size_t)bb*432 + 128)*512 + n] = u;
}

extern "C" void kernel_launch(void* const* d_in, const int* in_sizes, int n_in,
                              void* d_out, int out_size, void* d_ws, size_t ws_size,
                              hipStream_t stream) {
  const float* x     = (const float*)d_in[0];
  const float* x_his = (const float*)d_in[2];
  const float* y_cov = (const float*)d_in[3];
  const float* adj   = (const float*)d_in[4];
  const float* egW   = (const float*)d_in[5];
  const float* egb   = (const float*)d_in[6];
  const float* euW   = (const float*)d_in[7];
  const float* eub   = (const float*)d_in[8];
  const float* dgW   = (const float*)d_in[9];
  const float* dgb   = (const float*)d_in[10];
  const float* duW   = (const float*)d_in[11];
  const float* dub   = (const float*)d_in[12];
  const float* Mem   = (const float*)d_in[13];
  const float* Wq    = (const float*)d_in[14];
  const float* hW    = (const float*)d_in[15];
  const float* hb    = (const float*)d_in[16];
  const float* lW    = (const float*)d_in[17];
  const float* lb    = (const float*)d_in[18];
  const float* pW    = (const float*)d_in[19];
  const float* pb    = (const float*)d_in[20];
  float* out  = (float*)d_out;           // (64,12,512,1)
  float* outl = out + 393216;            // (64,512)

  char* base = (char*)d_ws;
  size_t off = 0;
  auto alloc = [&](size_t bytes)->char*{
    char* p = base + off; off = (off + bytes + 255) & ~(size_t)255; return p;
  };
  float* scratch = (float*)alloc(53477376);      // decoder-phase region:
  unsigned short* sup = (unsigned short*)scratch;           // 64*512*512 bf16
  float* emb = scratch + 8650752;                           // 32768*10 fp32
  int*   it  = (int*)(scratch + 9961472);                   // 32768
  int*   ih  = it + 32768;                                  // 32768
  float* henc = (float*)alloc(16777216);         // (128*512)x64 fp32, row-major
  float* zhF  = (float*)alloc(16777216);         // enc z*h (row-major); hCd alias
  float* hCd  = zhF;                             // (64,128,512) fp32 decoder state
  float* rbF  = (float*)alloc(16777216);         // enc r (row-major) / dec r (col-major)
  unsigned short* fR = (unsigned short*)alloc(29360128);  // 32768 x 448 bf16
  unsigned short* fC = (unsigned short*)alloc(28311552);  // 64 x 432 x 512 bf16
  float* a2e = (float*)alloc(1048576);           // 512x512 fp32
  float* wr_egF = (float*)alloc(104448);         // 204x128 fp32
  float* wr_euF = (float*)alloc(52224);          // 204x64 fp32
  unsigned short* wr_dg = (unsigned short*)alloc(229376); // 256x448 bf16
  unsigned short* wr_du = (unsigned short*)alloc(114688); // 128x448 bf16
  if (ws_size < off) return;

  // init (ws is re-poisoned every call)
  k_zero16<<<4096,256,0,stream>>>((uint4*)henc, 1048576);
  k_zero16<<<7168,256,0,stream>>>((uint4*)fR, 1835008);
  k_zero16<<<6912,256,0,stream>>>((uint4*)fC, 1769472);
  k_a2e<<<16,256,0,stream>>>(adj, a2e);
  k_reorderF<<<102,256,0,stream>>>(egW, wr_egF, 64,1,68,128);
  k_reorderF<<< 51,256,0,stream>>>(euW, wr_euF, 64,1,68,64);
  k_reorderB<<<448,256,0,stream>>>(dgW, wr_dg, 128,2,144,448,256);
  k_reorderB<<<224,256,0,stream>>>(duW, wr_du, 128,2,144,448,128);

  // ---------------- fp32 encoders: fused conv+gw, x|x_his paired ----------------
  for (int t = 0; t < 12; t++){
    k_enc<0><<<dim3(64,1,8),256,0,stream>>>(adj, a2e, henc, x, x_his, t,
                                            wr_egF, egb, zhF, rbF, nullptr);
    k_enc<1><<<dim3(64,1,8),256,0,stream>>>(adj, a2e, zhF, x, x_his, t,
                                            wr_euF, eub, nullptr, rbF, henc);
  }

  // ---------------- memory query / latent / support (fp32 scores) ----------------
  k_query<<<16384,256,0,stream>>>(henc, Wq, Mem, hCd, fR, fC, it, ih);
  k_latent<<<128,256,0,stream>>>(it, ih, Mem, lW, lb, outl);
  k_emb<<<128,256,0,stream>>>(hCd, hW, hb, emb);
  k_support<<<32768,256,0,stream>>>(emb, sup);
  k_fix_go<<<128,256,0,stream>>>(fR, fC);

  // ---------------- bf16 decoder, BB=64 ----------------
  for (int t = 0; t < 12; t++){
    k_extras_dec<<<128,256,0,stream>>>(y_cov, fR, fC, t);
    k_mmB<9,false><<<dim3(4,1,64),256,0,stream>>>(sup, 262144, fC, 432, 0, 1, fR, 448, 1.f);
    k_mmB<9,true ><<<dim3(4,1,64),256,0,stream>>>(sup, 262144, fC, 432, 1, 2, fR, 448, 2.f);
    k_gwB<14,16,0,128><<<dim3(256,1),256,0,stream>>>(fR, 448, wr_dg, dgb, fC, 432, hCd, rbF);
    k_mmB<9,false><<<dim3(4,1,64),256,0,stream>>>(sup, 262144, fC, 432, 0, 1, fR, 448, 1.f);
    k_mmB<9,true ><<<dim3(4,1,64),256,0,stream>>>(sup, 262144, fC, 432, 1, 2, fR, 448, 2.f);
    k_gwB<14,8,1,128><<<dim3(256,1),256,0,stream>>>(fR, 448, wr_du, dub, fC, 432, hCd, rbF);
    k_proj<<<128,256,0,stream>>>(hCd, pW, pb, fR, fC, out, t);
  }
}